// Round 6
// baseline (192.466 us; speedup 1.0000x reference)
//
#include <hip/hip_runtime.h>

constexpr int Bc = 8, Hc = 16, Sc = 4096, Dc = 64;
constexpr int BH = Bc * Hc;               // 128
constexpr int STG = 16;                   // rows staged per step
constexpr int MM = Dc * Dc;               // 4096 floats of M per (bh)
constexpr int QT = 128;                   // q-rows per block in k3

// ---- Kernel 1: M partial via 8x8 reg tiles, wave-split rows; z f64 spread over waves ----
template<int SSL>
__global__ __launch_bounds__(256, 4) void k1_accum(const float* __restrict__ K,
                                                   const float* __restrict__ V,
                                                   float* __restrict__ Pm,
                                                   double* __restrict__ Pz) {
  constexpr int CH = Sc / SSL;
  constexpr int NS = CH / STG;
  const int blk = blockIdx.x;
  const int bh = blk / SSL;
  const int ck = blk % SSL;
  const size_t base = ((size_t)bh * Sc + (size_t)ck * CH) * Dc;
  const float4* gk4 = (const float4*)(K + base);
  const float4* gv4 = (const float4*)(V + base);

  // smem: lk[2][16][64] at [buf*1024]; lv[2][16][64] at [2048 + buf*1024]  (16 KB total)
  __shared__ __align__(16) float smem[4096];

  const int tid = threadIdx.x;
  const int w = tid >> 6;        // wave 0..3 (owns rows w*4..w*4+3 of each stage)
  const int l = tid & 63;
  const int d0 = (l >> 3) * 8;   // tile rows (k-dim)
  const int e0 = (l & 7) * 8;    // tile cols (v-dim)

  float acc[8][8] = {};          // per-wave partial of M[d0..+8][e0..+8]
  double zacc = 0.0;             // exact z partial (order-free)

  const int srow = tid >> 4;           // staging row 0..15
  const int scol = (tid & 15) * 4;     // staging col (floats)

  // prologue: stage 0
  float4 rk = gk4[tid], rv = gv4[tid];
  *(float4*)&smem[srow * 64 + scol] = rk;
  *(float4*)&smem[2048 + srow * 64 + scol] = rv;
  __syncthreads();

  for (int st = 0; st < NS; ++st) {
    const int cur = st & 1, nxt = cur ^ 1;
    if (st + 1 < NS) {               // issue next-stage loads early (hide under compute)
      rk = gk4[(st + 1) * 256 + tid];
      rv = gv4[(st + 1) * 256 + tid];
    }
    const float* lkc = &smem[cur * 1024];
    const float* lvc = &smem[2048 + cur * 1024];
    #pragma unroll
    for (int r = 0; r < 4; ++r) {
      const int row = w * 4 + r;
      const float4 ka = *(const float4*)&lkc[row * 64 + d0];
      const float4 kb = *(const float4*)&lkc[row * 64 + d0 + 4];
      const float4 va = *(const float4*)&lvc[row * 64 + e0];
      const float4 vb = *(const float4*)&lvc[row * 64 + e0 + 4];
      const float kk[8] = {ka.x, ka.y, ka.z, ka.w, kb.x, kb.y, kb.z, kb.w};
      const float vv[8] = {va.x, va.y, va.z, va.w, vb.x, vb.y, vb.z, vb.w};
      #pragma unroll
      for (int a = 0; a < 8; ++a)
        #pragma unroll
        for (int b = 0; b < 8; ++b)
          acc[a][b] = fmaf(kk[a], vv[b], acc[a][b]);
    }
    // z: wave w sums its 4 rows, lane l handles d = l (consecutive -> conflict-free)
    #pragma unroll
    for (int r = 0; r < 4; ++r)
      zacc += (double)lkc[(w * 4 + r) * 64 + l];
    // write next stage late (vmcnt wait overlapped with the compute above)
    if (st + 1 < NS) {
      *(float4*)&smem[nxt * 1024 + srow * 64 + scol] = rk;
      *(float4*)&smem[2048 + nxt * 1024 + srow * 64 + scol] = rv;
    }
    __syncthreads();   // single barrier per stage (dbuf: reads=cur, writes=nxt)
  }

  // combine 4 wave-partials of M in smem (serial over waves; amortized once/block)
  #pragma unroll
  for (int p = 0; p < 4; ++p) {
    if (w == p) {
      #pragma unroll
      for (int a = 0; a < 8; ++a) {
        float* dst = &smem[(d0 + a) * 64 + e0];
        float4 lo = make_float4(acc[a][0], acc[a][1], acc[a][2], acc[a][3]);
        float4 hi = make_float4(acc[a][4], acc[a][5], acc[a][6], acc[a][7]);
        if (p == 0) {
          *(float4*)dst = lo; *(float4*)(dst + 4) = hi;
        } else {
          float4 olo = *(float4*)dst, ohi = *(float4*)(dst + 4);
          olo.x += lo.x; olo.y += lo.y; olo.z += lo.z; olo.w += lo.w;
          ohi.x += hi.x; ohi.y += hi.y; ohi.z += hi.z; ohi.w += hi.w;
          *(float4*)dst = olo; *(float4*)(dst + 4) = ohi;
        }
      }
    }
    __syncthreads();
  }

  // coalesced Pm write from smem
  float* pd = Pm + ((size_t)ck * BH + bh) * MM;
  #pragma unroll
  for (int j = 0; j < 4; ++j) {
    const int idx = tid + j * 256;
    ((float4*)pd)[idx] = *(const float4*)&smem[idx * 4];
  }
  Pz[((size_t)(ck * 4 + w) * BH + bh) * Dc + l] = zacc;
}

// ---- Kernel 2: reduce M partials (f32); z = f64 exact sum ROUNDED TO F32 ----
__global__ __launch_bounds__(256) void k2_reduce(const float* __restrict__ Pm,
                                                 const double* __restrict__ Pz,
                                                 float* __restrict__ Fm,
                                                 float* __restrict__ Fz,
                                                 int ss) {
  const int i = blockIdx.x * 256 + threadIdx.x;
  const int nm = BH * MM;
  if (i < nm) {
    float s = 0.f;
    for (int c = 0; c < ss; ++c) s += Pm[(size_t)c * nm + i];
    Fm[i] = s;
  }
  const int nz = BH * Dc;
  if (i < nz) {
    double s = 0.0;
    const int np = ss * 4;
    for (int c = 0; c < np; ++c) s += Pz[(size_t)c * nz + i];
    Fz[i] = (float)s;   // f32 intermediate matches np bitwise
  }
}

// ---- Kernel 3: out = (q @ M) / (q . z_f32 + eps); 4 rows x 8 cols per thread ----
__global__ __launch_bounds__(256) void k3_retrieve(const float* __restrict__ Q,
                                                   const float* __restrict__ Fm,
                                                   const float* __restrict__ Fz,
                                                   float* __restrict__ O) {
  const int blk = blockIdx.x;             // BH * (Sc/QT) = 128*32
  const int bh = blk >> 5;
  const int row0 = (blk & 31) * QT;

  __shared__ __align__(16) float lm[Dc][Dc];     // 16 KB
  __shared__ __align__(16) float lq[QT][68];     // padded: row stride 68 floats
  __shared__ __align__(16) float lz[Dc];         // f32 z (the np intermediate)

  const int tid = threadIdx.x;

  // stage M: contiguous 16 KB
  const float4* gm4 = (const float4*)(Fm + (size_t)bh * MM);
  float4* lm4 = (float4*)&lm[0][0];
  #pragma unroll
  for (int j = 0; j < 4; ++j) lm4[tid + j * 256] = gm4[tid + j * 256];
  if (tid < Dc) lz[tid] = Fz[(size_t)bh * Dc + tid];

  // stage q rows (coalesced global, padded LDS rows)
  const float4* gq4 = (const float4*)(Q + ((size_t)bh * Sc + row0) * Dc);
  #pragma unroll
  for (int j = 0; j < 8; ++j) {
    const int i4 = tid + j * 256;
    const float4 v = gq4[i4];
    const int f = i4 * 4;
    *(float4*)&lq[f >> 6][f & 63] = v;
  }
  __syncthreads();

  const int rg = tid >> 3;       // 0..31 -> row quad
  const int cg = tid & 7;        // 0..7  -> 8-col block
  const int r0 = rg * 4;
  const int e0 = cg * 8;

  float acc[4][8] = {};
  double den[4] = {0.0, 0.0, 0.0, 0.0};

  #pragma unroll
  for (int ds = 0; ds < 16; ++ds) {
    const int d0 = ds * 4;
    const float4 z4 = *(const float4*)&lz[d0];
    const float* zf = (const float*)&z4;
    float4 q4[4];
    #pragma unroll
    for (int r = 0; r < 4; ++r) q4[r] = *(const float4*)&lq[r0 + r][d0];
    const float* qf[4] = {(const float*)&q4[0], (const float*)&q4[1],
                          (const float*)&q4[2], (const float*)&q4[3]};
    #pragma unroll
    for (int i = 0; i < 4; ++i) {
      const float4 ma = *(const float4*)&lm[d0 + i][e0];
      const float4 mb = *(const float4*)&lm[d0 + i][e0 + 4];
      const float mf[8] = {ma.x, ma.y, ma.z, ma.w, mb.x, mb.y, mb.z, mb.w};
      const double zd = (double)zf[i];
      #pragma unroll
      for (int r = 0; r < 4; ++r) {
        const float qs = qf[r][i];
        den[r] += (double)qs * zd;
        #pragma unroll
        for (int j = 0; j < 8; ++j)
          acc[r][j] = fmaf(qs, mf[j], acc[r][j]);
      }
    }
  }

  #pragma unroll
  for (int r = 0; r < 4; ++r) {
    const double iv = 1.0 / (den[r] + 1e-6);
    float* go = O + ((size_t)bh * Sc + row0 + r0 + r) * Dc + e0;
    ((float4*)go)[0] = make_float4((float)((double)acc[r][0] * iv),
                                   (float)((double)acc[r][1] * iv),
                                   (float)((double)acc[r][2] * iv),
                                   (float)((double)acc[r][3] * iv));
    ((float4*)go)[1] = make_float4((float)((double)acc[r][4] * iv),
                                   (float)((double)acc[r][5] * iv),
                                   (float)((double)acc[r][6] * iv),
                                   (float)((double)acc[r][7] * iv));
  }
}

extern "C" void kernel_launch(void* const* d_in, const int* in_sizes, int n_in,
                              void* d_out, int out_size, void* d_ws, size_t ws_size,
                              hipStream_t stream) {
  const float* K = (const float*)d_in[0];   // keys    [B,H,S,D]
  const float* V = (const float*)d_in[1];   // values
  const float* Q = (const float*)d_in[2];   // queries
  float* O = (float*)d_out;                 // [B,H,S,D]

  // Pick SS by available scratch (deterministic: ws_size fixed across calls).
  // SS=16 needs: Pm 33.55MB + Fm 2.10MB + Pz 4.19MB + Fz 0.03MB ~= 39.9MB.
  const size_t need16 = (size_t)16 * BH * MM * 4 + (size_t)BH * MM * 4 +
                        (size_t)16 * 4 * BH * Dc * 8 + (size_t)BH * Dc * 4;
  const int ss = (ws_size >= need16) ? 16 : 8;

  float* Pm = (float*)d_ws;                                  // ss*BH*MM floats
  float* Fm = Pm + (size_t)ss * BH * MM;                     // BH*MM floats
  double* Pz = (double*)(Fm + (size_t)BH * MM);              // ss*4*BH*Dc doubles
  float* Fz = (float*)(Pz + (size_t)ss * 4 * BH * Dc);       // BH*Dc floats

  if (ss == 16)
    hipLaunchKernelGGL(k1_accum<16>, dim3(BH * 16), dim3(256), 0, stream, K, V, Pm, Pz);
  else
    hipLaunchKernelGGL(k1_accum<8>, dim3(BH * 8), dim3(256), 0, stream, K, V, Pm, Pz);
  hipLaunchKernelGGL(k2_reduce, dim3((BH * MM + 255) / 256), dim3(256), 0, stream, Pm, Pz, Fm, Fz, ss);
  hipLaunchKernelGGL(k3_retrieve, dim3(BH * (Sc / QT)), dim3(256), 0, stream, Q, Fm, Fz, O);
}